// Round 2
// baseline (1187.465 us; speedup 1.0000x reference)
//
#include <hip/hip_runtime.h>
#include <hip/hip_bf16.h>

// Problem constants
#define N_ROWS 65536   // 16*4096
#define EDIM   512
#define NCODES 1024

// Tiling
#define ROWS_PER_BLOCK 128
#define CODE_CHUNK     64
#define KCHUNK         32
#define ZSTRIDE        132   // 128 + 4 pad
#define ESTRIDE        68    // 64 + 4 pad

// ws layout (floats): [0]=loss, [1..1025)=counts, [1025..2049)=enorm, [2049..)=znorm
#define WS_LOSS   0
#define WS_COUNTS 1
#define WS_ENORM  1025
#define WS_ZNORM  2049

// ---------------- kernel 0: codebook norms + zero accumulators ----------------
__global__ __launch_bounds__(256) void vq_prep(const float* __restrict__ cb,
                                               float* __restrict__ ws) {
    int j = blockIdx.x;
    int tid = threadIdx.x;
    float2 v = *(const float2*)&cb[(size_t)j * EDIM + tid * 2];
    float s = v.x * v.x + v.y * v.y;
    #pragma unroll
    for (int off = 32; off > 0; off >>= 1) s += __shfl_down(s, off);
    __shared__ float ls[4];
    int wave = tid >> 6, lane = tid & 63;
    if (lane == 0) ls[wave] = s;
    __syncthreads();
    if (tid == 0) {
        ws[WS_ENORM + j] = ls[0] + ls[1] + ls[2] + ls[3];
        ws[WS_COUNTS + j] = 0.0f;
        if (j == 0) ws[WS_LOSS] = 0.0f;
    }
}

// ---------------- kernel 0b: per-row ||z||^2, numpy-pairwise bit-exact ----------------
// numpy pairwise for n=512 (contiguous): perfect binary tree over 32 chains,
// chain c (b=c>>3, j=c&7) = sequential sum of z[128b + 8i + j]^2, i=0..15;
// combine = xor-tree over lanes (matches numpy's association exactly).
__global__ __launch_bounds__(256) void vq_znorm(const float* __restrict__ z,
                                                float* __restrict__ ws) {
    int tid  = threadIdx.x;
    int lrow = tid >> 5;          // 8 rows per block
    int c    = tid & 31;          // chain id
    long row = (long)blockIdx.x * 8 + lrow;
    const float* p = z + row * EDIM + (c >> 3) * 128 + (c & 7);
    float r = p[0] * p[0];
    #pragma unroll
    for (int i = 1; i < 16; ++i) {
        float v = p[i * 8];
        r += v * v;
    }
    r += __shfl_xor(r, 1);
    r += __shfl_xor(r, 2);
    r += __shfl_xor(r, 4);
    r += __shfl_xor(r, 8);
    r += __shfl_xor(r, 16);
    if (c == 0) ws[WS_ZNORM + row] = r;
}

// ---------------- kernel 1: fused distances + argmin + gather + loss ----------------
__global__ __launch_bounds__(256) void vq_main(const float* __restrict__ z,
                                               const float* __restrict__ cb,
                                               float* __restrict__ ws,
                                               float* __restrict__ out_zq,
                                               float* __restrict__ out_idx) {
    __shared__ float zt[KCHUNK * ZSTRIDE];
    __shared__ float et[KCHUNK * ESTRIDE];
    __shared__ float red_d[ROWS_PER_BLOCK * 8];
    __shared__ int   red_i[ROWS_PER_BLOCK * 8];
    __shared__ int   winner[ROWS_PER_BLOCK];
    __shared__ float lred[4];

    const int tid = threadIdx.x;
    const int tx = tid & 7;       // 8 codes
    const int ty = tid >> 3;      // 4 rows
    const long row0 = (long)blockIdx.x * ROWS_PER_BLOCK;
    const float* __restrict__ enorm = ws + WS_ENORM;
    const float* __restrict__ znorm = ws + WS_ZNORM;

    float zn[4];
    #pragma unroll
    for (int i = 0; i < 4; ++i) zn[i] = znorm[row0 + ty * 4 + i];

    float best[4];
    int   bidx[4];
    #pragma unroll
    for (int i = 0; i < 4; ++i) { best[i] = INFINITY; bidx[i] = 0; }

    const int kq    = (tid & 7) * 4;
    const int rbase = tid >> 3;

    for (int c = 0; c < NCODES; c += CODE_CHUNK) {
        float acc[4][8];
        #pragma unroll
        for (int i = 0; i < 4; ++i)
            #pragma unroll
            for (int j = 0; j < 8; ++j) acc[i][j] = 0.0f;

        for (int k0 = 0; k0 < EDIM; k0 += KCHUNK) {
            __syncthreads();
            #pragma unroll
            for (int it = 0; it < 4; ++it) {
                int r = rbase + it * 32;
                float4 v = *(const float4*)&z[(row0 + r) * EDIM + k0 + kq];
                zt[(kq + 0) * ZSTRIDE + r] = v.x;
                zt[(kq + 1) * ZSTRIDE + r] = v.y;
                zt[(kq + 2) * ZSTRIDE + r] = v.z;
                zt[(kq + 3) * ZSTRIDE + r] = v.w;
            }
            #pragma unroll
            for (int it = 0; it < 2; ++it) {
                int e = rbase + it * 32;
                float4 v = *(const float4*)&cb[(size_t)(c + e) * EDIM + k0 + kq];
                et[(kq + 0) * ESTRIDE + e] = v.x;
                et[(kq + 1) * ESTRIDE + e] = v.y;
                et[(kq + 2) * ESTRIDE + e] = v.z;
                et[(kq + 3) * ESTRIDE + e] = v.w;
            }
            __syncthreads();
            // two-level accumulation: fresh inner accumulator per 32-k chunk
            float ain[4][8];
            #pragma unroll
            for (int i = 0; i < 4; ++i)
                #pragma unroll
                for (int j = 0; j < 8; ++j) ain[i][j] = 0.0f;
            #pragma unroll
            for (int kk = 0; kk < KCHUNK; ++kk) {
                float4 zv = *(const float4*)&zt[kk * ZSTRIDE + ty * 4];
                float4 e0 = *(const float4*)&et[kk * ESTRIDE + tx * 8];
                float4 e1 = *(const float4*)&et[kk * ESTRIDE + tx * 8 + 4];
                float za[4] = {zv.x, zv.y, zv.z, zv.w};
                float ea[8] = {e0.x, e0.y, e0.z, e0.w, e1.x, e1.y, e1.z, e1.w};
                #pragma unroll
                for (int i = 0; i < 4; ++i)
                    #pragma unroll
                    for (int j = 0; j < 8; ++j)
                        ain[i][j] = fmaf(za[i], ea[j], ain[i][j]);
            }
            #pragma unroll
            for (int i = 0; i < 4; ++i)
                #pragma unroll
                for (int j = 0; j < 8; ++j) acc[i][j] += ain[i][j];
        }
        // d = fl32( fl32(znorm + enorm) - 2*dot )  — exactly the np rounding chain
        #pragma unroll
        for (int j = 0; j < 8; ++j) {
            int code = c + tx * 8 + j;
            float en = enorm[code];
            #pragma unroll
            for (int i = 0; i < 4; ++i) {
                float t = zn[i] + en;                 // fp32 round (np: A+B)
                float d = t - 2.0f * acc[i][j];       // 2*acc exact, one round
                if (d < best[i]) { best[i] = d; bidx[i] = code; }  // first-min
            }
        }
    }

    __syncthreads();
    #pragma unroll
    for (int i = 0; i < 4; ++i) {
        red_d[(ty * 4 + i) * 8 + tx] = best[i];
        red_i[(ty * 4 + i) * 8 + tx] = bidx[i];
    }
    __syncthreads();
    if (tid < ROWS_PER_BLOCK) {
        float bd = red_d[tid * 8];
        int   bi = red_i[tid * 8];
        #pragma unroll
        for (int t = 1; t < 8; ++t) {
            float dv = red_d[tid * 8 + t];
            int   iv = red_i[tid * 8 + t];
            if (dv < bd || (dv == bd && iv < bi)) { bd = dv; bi = iv; }
        }
        winner[tid] = bi;
        out_idx[row0 + tid] = (float)bi;
        atomicAdd(&ws[WS_COUNTS + bi], 1.0f);
    }
    __syncthreads();

    // gather z_q_st = z + (z_q - z)  (two fp32 roundings, matches np) + loss
    float lsum = 0.0f;
    for (int r = 0; r < ROWS_PER_BLOCK; ++r) {
        int w = winner[r];
        float2 e  = *(const float2*)&cb[(size_t)w * EDIM + tid * 2];
        float2 zz = *(const float2*)&z[(row0 + r) * EDIM + tid * 2];
        float d0 = e.x - zz.x, d1 = e.y - zz.y;
        float2 o; o.x = zz.x + d0; o.y = zz.y + d1;
        *(float2*)&out_zq[(row0 + r) * EDIM + tid * 2] = o;
        lsum = fmaf(d0, d0, fmaf(d1, d1, lsum));
    }
    #pragma unroll
    for (int off = 32; off > 0; off >>= 1) lsum += __shfl_down(lsum, off);
    int wave = tid >> 6, lane = tid & 63;
    if (lane == 0) lred[wave] = lsum;
    __syncthreads();
    if (tid == 0) atomicAdd(&ws[WS_LOSS], lred[0] + lred[1] + lred[2] + lred[3]);
}

// ---------------- kernel 2: finalize loss + perplexity ----------------
__global__ __launch_bounds__(1024) void vq_final(const float* __restrict__ ws,
                                                 float* __restrict__ out,
                                                 long off_perp) {
    int tid = threadIdx.x;
    float c = ws[WS_COUNTS + tid] * (1.0f / (float)N_ROWS);
    float t = c * logf(c + 1e-10f);
    #pragma unroll
    for (int off = 32; off > 0; off >>= 1) t += __shfl_down(t, off);
    __shared__ float ls[16];
    int wave = tid >> 6, lane = tid & 63;
    if (lane == 0) ls[wave] = t;
    __syncthreads();
    if (tid == 0) {
        float h = 0.0f;
        #pragma unroll
        for (int i = 0; i < 16; ++i) h += ls[i];
        out[off_perp] = expf(-h);
        out[0] = ws[WS_LOSS] * 1.25f / (float)((long)N_ROWS * EDIM);
    }
}

extern "C" void kernel_launch(void* const* d_in, const int* in_sizes, int n_in,
                              void* d_out, int out_size, void* d_ws, size_t ws_size,
                              hipStream_t stream) {
    const float* z  = (const float*)d_in[0];
    const float* cb = (const float*)d_in[1];
    float* out = (float*)d_out;
    float* ws  = (float*)d_ws;

    float* out_zq  = out + 1;
    float* out_idx = out + 1 + (long)N_ROWS * EDIM;
    long   off_perp = 1 + (long)N_ROWS * EDIM + N_ROWS;

    hipLaunchKernelGGL(vq_prep, dim3(NCODES), dim3(256), 0, stream, cb, ws);
    hipLaunchKernelGGL(vq_znorm, dim3(N_ROWS / 8), dim3(256), 0, stream, z, ws);
    hipLaunchKernelGGL(vq_main, dim3(N_ROWS / ROWS_PER_BLOCK), dim3(256), 0, stream,
                       z, cb, ws, out_zq, out_idx);
    hipLaunchKernelGGL(vq_final, dim3(1), dim3(1024), 0, stream, ws, out, off_perp);
}